// Round 1
// baseline (577.696 us; speedup 1.0000x reference)
//
#include <hip/hip_runtime.h>

#define NROWS 8192
#define DDIM  128

constexpr int BM = 64;        // rows per block
constexpr int BN = 128;       // cols per j-tile
constexpr int BK = 32;        // k-chunk for B staging
constexpr int CSPLIT = 8;     // column slices -> grid = 128*8 = 1024 blocks
constexpr int COLS = NROWS / CSPLIT;   // 1024 cols per block
constexpr int NJT  = COLS / BN;        // 8 j-tiles per block

// Kernel A: L2-normalize pred and neg per row; emit p (normalized pred),
// sq[i] = sum(p_i^2), nd[i] = safe_sqrt(sum((p_i - n_i)^2)).
// One wave per row (64 lanes x float2 = 128 elems).
__global__ __launch_bounds__(256) void norm_kernel(
    const float* __restrict__ pred, const float* __restrict__ neg,
    float* __restrict__ p, float* __restrict__ sq, float* __restrict__ nd) {
  int wave = threadIdx.x >> 6;
  int lane = threadIdx.x & 63;
  int row = blockIdx.x * 4 + wave;
  const float2* pr = (const float2*)(pred + (size_t)row * DDIM);
  const float2* nr = (const float2*)(neg + (size_t)row * DDIM);
  float2 x = pr[lane];
  float2 y = nr[lane];
  float sx = x.x * x.x + x.y * x.y;
  float sy = y.x * y.x + y.y * y.y;
#pragma unroll
  for (int off = 32; off; off >>= 1) {
    sx += __shfl_xor(sx, off);
    sy += __shfl_xor(sy, off);
  }
  float invx = 1.0f / fmaxf(sqrtf(sx), 1e-12f);
  float invy = 1.0f / fmaxf(sqrtf(sy), 1e-12f);
  float2 px = make_float2(x.x * invx, x.y * invx);
  float2 pn = make_float2(y.x * invy, y.y * invy);
  ((float2*)(p + (size_t)row * DDIM))[lane] = px;
  float dx = px.x - pn.x, dy = px.y - pn.y;
  float sd = dx * dx + dy * dy;
  float sp = px.x * px.x + px.y * px.y;
#pragma unroll
  for (int off = 32; off; off >>= 1) {
    sd += __shfl_xor(sd, off);
    sp += __shfl_xor(sp, off);
  }
  if (lane == 0) {
    nd[row] = sd > 0.0f ? sqrtf(sd) : 0.0f;  // safe_sqrt semantics
    sq[row] = sp;
  }
}

// Kernel B: fused gram-tile + masked-distance accumulation.
// Block owns BM=64 rows and a 1024-col slice. A tile (64x128 K) staged
// transposed in LDS once; B tiles staged transposed per (j-tile, k-chunk).
// Thread computes 4 rows x 8 cols; epilogue does d2 -> safe_sqrt -> *mask
// and accumulates per-row pos_sum / cnt partials, reduced via 16-lane shfl.
__global__ __launch_bounds__(256) void pair_kernel(
    const float* __restrict__ p, const float* __restrict__ sq,
    const float* __restrict__ mask,
    float* __restrict__ pos_sum, float* __restrict__ cnt) {
  __shared__ float aT[DDIM][BM + 4];   // [128][68] transposed: aT[k][row]
  __shared__ float bT[BK][BN + 4];     // [32][132]  transposed: bT[k][col]
  const int t = threadIdx.x;
  const int ib = blockIdx.x >> 3;           // row block 0..127
  const int cs = blockIdx.x & (CSPLIT - 1); // col slice 0..7
  const int i0 = ib * BM;
  const int j00 = cs * COLS;

  // stage aT: 64 rows x 128 K = 2048 float4, 8 per thread
#pragma unroll
  for (int q0 = 0; q0 < BM * DDIM / 4; q0 += 256) {
    int q = q0 + t;
    int row = q >> 5;       // 32 float4 per row
    int kq = q & 31;
    float4 v = *(const float4*)(p + (size_t)(i0 + row) * DDIM + kq * 4);
    aT[kq * 4 + 0][row] = v.x;
    aT[kq * 4 + 1][row] = v.y;
    aT[kq * 4 + 2][row] = v.z;
    aT[kq * 4 + 3][row] = v.w;
  }
  const int rg = t >> 4;   // row group: rows i0 + 4*rg .. +3
  const int cg = t & 15;   // col group: cols j0 + 8*cg .. +7
  float sqi[4];
#pragma unroll
  for (int s = 0; s < 4; ++s) sqi[s] = sq[i0 + 4 * rg + s];
  float pos_part[4] = {0.f, 0.f, 0.f, 0.f};
  float cnt_part[4] = {0.f, 0.f, 0.f, 0.f};

  for (int jt = 0; jt < NJT; ++jt) {
    const int j0 = j00 + jt * BN;
    float acc[4][8];
#pragma unroll
    for (int s = 0; s < 4; ++s)
#pragma unroll
      for (int u = 0; u < 8; ++u) acc[s][u] = 0.f;

    for (int kc = 0; kc < DDIM / BK; ++kc) {
      __syncthreads();  // protect bT from previous readers
#pragma unroll
      for (int q0 = 0; q0 < BN * BK / 4; q0 += 256) {
        int q = q0 + t;
        int col = q >> 3;   // 8 float4 per col-chunk
        int kq = q & 7;
        float4 v = *(const float4*)(p + (size_t)(j0 + col) * DDIM + kc * BK + kq * 4);
        bT[kq * 4 + 0][col] = v.x;
        bT[kq * 4 + 1][col] = v.y;
        bT[kq * 4 + 2][col] = v.z;
        bT[kq * 4 + 3][col] = v.w;
      }
      __syncthreads();
#pragma unroll
      for (int k = 0; k < BK; ++k) {
        float4 a4 = *(const float4*)&aT[kc * BK + k][4 * rg];
        float4 b0 = *(const float4*)&bT[k][8 * cg];
        float4 b1 = *(const float4*)&bT[k][8 * cg + 4];
        float av[4] = {a4.x, a4.y, a4.z, a4.w};
        float bv[8] = {b0.x, b0.y, b0.z, b0.w, b1.x, b1.y, b1.z, b1.w};
#pragma unroll
        for (int s = 0; s < 4; ++s)
#pragma unroll
          for (int u = 0; u < 8; ++u)
            acc[s][u] = fmaf(av[s], bv[u], acc[s][u]);
      }
    }
    // epilogue for this j-tile
    float sqj[8];
#pragma unroll
    for (int u = 0; u < 8; ++u) sqj[u] = sq[j0 + 8 * cg + u];
#pragma unroll
    for (int s = 0; s < 4; ++s) {
      const float* mrow = mask + (size_t)(i0 + 4 * rg + s) * NROWS + j0 + 8 * cg;
      float4 m0 = *(const float4*)(mrow);
      float4 m1 = *(const float4*)(mrow + 4);
      float mv[8] = {m0.x, m0.y, m0.z, m0.w, m1.x, m1.y, m1.z, m1.w};
#pragma unroll
      for (int u = 0; u < 8; ++u) {
        float d2 = sqi[s] + sqj[u] - 2.0f * acc[s][u];
        float dist = d2 > 0.0f ? sqrtf(d2) : 0.0f;
        pos_part[s] = fmaf(dist, mv[u], pos_part[s]);
        cnt_part[s] += mv[u];
      }
    }
  }
  // reduce across the 16 lanes that share this row group
#pragma unroll
  for (int s = 0; s < 4; ++s) {
#pragma unroll
    for (int off = 1; off < 16; off <<= 1) {
      pos_part[s] += __shfl_xor(pos_part[s], off);
      cnt_part[s] += __shfl_xor(cnt_part[s], off);
    }
  }
  if ((t & 15) == 0) {
#pragma unroll
    for (int s = 0; s < 4; ++s) {
      atomicAdd(&pos_sum[i0 + 4 * rg + s], pos_part[s]);
      atomicAdd(&cnt[i0 + 4 * rg + s], cnt_part[s]);
    }
  }
}

// Kernel C: final mean(pos_avg - nd) in double.
__global__ __launch_bounds__(256) void finalize_kernel(
    const float* __restrict__ pos_sum, const float* __restrict__ cnt,
    const float* __restrict__ nd, float* __restrict__ out) {
  __shared__ double sdata[256];
  double a = 0.0;
  for (int r = threadIdx.x; r < NROWS; r += 256) {
    float c = fmaxf(cnt[r], 1.0f);
    a += (double)(pos_sum[r] / c) - (double)nd[r];
  }
  sdata[threadIdx.x] = a;
  __syncthreads();
  for (int s2 = 128; s2 > 0; s2 >>= 1) {
    if (threadIdx.x < s2) sdata[threadIdx.x] += sdata[threadIdx.x + s2];
    __syncthreads();
  }
  if (threadIdx.x == 0) out[0] = (float)(sdata[0] / NROWS);
}

extern "C" void kernel_launch(void* const* d_in, const int* in_sizes, int n_in,
                              void* d_out, int out_size, void* d_ws, size_t ws_size,
                              hipStream_t stream) {
  const float* pred = (const float*)d_in[0];
  const float* mask = (const float*)d_in[1];
  const float* neg  = (const float*)d_in[2];
  float* out = (float*)d_out;

  float* p   = (float*)d_ws;                        // N*D floats
  float* sq  = p + (size_t)NROWS * DDIM;            // N
  float* nd  = sq + NROWS;                          // N
  float* pos = nd + NROWS;                          // N
  float* cnt = pos + NROWS;                         // N  (contiguous with pos)

  hipMemsetAsync(pos, 0, 2 * NROWS * sizeof(float), stream);
  norm_kernel<<<NROWS / 4, 256, 0, stream>>>(pred, neg, p, sq, nd);
  pair_kernel<<<(NROWS / BM) * CSPLIT, 256, 0, stream>>>(p, sq, mask, pos, cnt);
  finalize_kernel<<<1, 256, 0, stream>>>(pos, cnt, nd, out);
}

// Round 2
// 469.217 us; speedup vs baseline: 1.2312x; 1.2312x over previous
//
#include <hip/hip_runtime.h>

#define N 8192
#define D 128

typedef __attribute__((ext_vector_type(8))) short bf16x8;
typedef __attribute__((ext_vector_type(4))) float f32x4;

__device__ __forceinline__ unsigned short f32_to_bf16_rne(float f) {
  unsigned int u = __float_as_uint(f);
  unsigned int r = (u + 0x7FFFu + ((u >> 16) & 1u)) >> 16;
  return (unsigned short)r;
}
__device__ __forceinline__ float bf16_to_f32(unsigned short h) {
  return __uint_as_float(((unsigned int)h) << 16);
}

// global -> LDS direct copy, 16B per lane, NT cache policy (aux=2) so the
// streamed mask does not evict phi/plo from L2/L3.
__device__ __forceinline__ void load_lds16_nt(const void* g, void* l) {
  __builtin_amdgcn_global_load_lds((const __attribute__((address_space(1))) void*)g,
                                   (__attribute__((address_space(3))) void*)l,
                                   16, 0, 2);
}

// Kernel A: L2-normalize pred/neg; emit phi/plo (bf16 hi/lo split of normalized
// pred), sq[i]=sum(p^2) fp32, nd[i]=safe_sqrt(sum((p-n)^2)). One wave per row.
__global__ __launch_bounds__(256) void norm_kernel(
    const float* __restrict__ pred, const float* __restrict__ neg,
    unsigned short* __restrict__ phi, unsigned short* __restrict__ plo,
    float* __restrict__ sq, float* __restrict__ nd) {
  int wv = threadIdx.x >> 6;
  int lane = threadIdx.x & 63;
  int row = blockIdx.x * 4 + wv;
  float2 x = ((const float2*)(pred + (size_t)row * D))[lane];
  float2 y = ((const float2*)(neg + (size_t)row * D))[lane];
  float sx = x.x * x.x + x.y * x.y;
  float sy = y.x * y.x + y.y * y.y;
#pragma unroll
  for (int off = 32; off; off >>= 1) {
    sx += __shfl_xor(sx, off);
    sy += __shfl_xor(sy, off);
  }
  float invx = 1.0f / fmaxf(sqrtf(sx), 1e-12f);
  float invy = 1.0f / fmaxf(sqrtf(sy), 1e-12f);
  float2 px = make_float2(x.x * invx, x.y * invx);
  float2 pn = make_float2(y.x * invy, y.y * invy);

  unsigned short h0 = f32_to_bf16_rne(px.x), h1 = f32_to_bf16_rne(px.y);
  unsigned short l0 = f32_to_bf16_rne(px.x - bf16_to_f32(h0));
  unsigned short l1 = f32_to_bf16_rne(px.y - bf16_to_f32(h1));
  ushort2 hv; hv.x = h0; hv.y = h1;
  ushort2 lv; lv.x = l0; lv.y = l1;
  ((ushort2*)(phi + (size_t)row * D))[lane] = hv;
  ((ushort2*)(plo + (size_t)row * D))[lane] = lv;

  float sp = px.x * px.x + px.y * px.y;
  float dx = px.x - pn.x, dy = px.y - pn.y;
  float sd = dx * dx + dy * dy;
#pragma unroll
  for (int off = 32; off; off >>= 1) {
    sp += __shfl_xor(sp, off);
    sd += __shfl_xor(sd, off);
  }
  if (lane == 0) {
    sq[row] = sp;
    nd[row] = sd > 0.0f ? sqrtf(sd) : 0.0f;
  }
}

// Kernel B: 128x128 tile per block; 4 waves in 2x2, each wave a 64x64 output
// via 4x4 fragments of mfma_f32_16x16x32_bf16 with hi/lo 3-way split.
// Mask tile prefetched to LDS (NT) interleaved with the k-loop; epilogue does
// d2 -> safe_sqrt -> mask-weighted row partials -> per-(jb,row) global partials.
__global__ __launch_bounds__(256, 2) void pair_kernel(
    const unsigned short* __restrict__ phi, const unsigned short* __restrict__ plo,
    const float* __restrict__ sq, const float* __restrict__ mask,
    float* __restrict__ ppos, float* __restrict__ pcnt) {
  __shared__ float smask[128 * 128];  // 64 KB; tail 512 floats reused for combine

  const int bid = blockIdx.x;
  const int swz = (bid & 7) * 512 + (bid >> 3);  // XCD-aware, bijective (4096%8==0)
  const int ib = swz >> 6, jb = swz & 63;
  const int i0 = ib * 128, j0 = jb * 128;

  const int t = threadIdx.x;
  const int wv = t >> 6, lane = t & 63;
  const int wi = wv >> 1, wj = wv & 1;
  const int lr = lane & 15, lk = lane >> 4;

  const int arow = i0 + wi * 64 + lr;  // + fi*16
  const int brow = j0 + wj * 64 + lr;  // + fj*16

  f32x4 acc[4][4];
#pragma unroll
  for (int a = 0; a < 4; ++a)
#pragma unroll
    for (int b = 0; b < 4; ++b) acc[a][b] = (f32x4){0.f, 0.f, 0.f, 0.f};

  for (int kc = 0; kc < 4; ++kc) {
    const int kb = kc * 32 + lk * 8;
    bf16x8 ah[4], al[4], bh[4], bl[4];
#pragma unroll
    for (int f = 0; f < 4; ++f) {
      ah[f] = *(const bf16x8*)(phi + (size_t)(arow + f * 16) * D + kb);
      al[f] = *(const bf16x8*)(plo + (size_t)(arow + f * 16) * D + kb);
      bh[f] = *(const bf16x8*)(phi + (size_t)(brow + f * 16) * D + kb);
      bl[f] = *(const bf16x8*)(plo + (size_t)(brow + f * 16) * D + kb);
    }
    // stage 8 mask rows per wave per k-step (rows wv*32 .. wv*32+31 overall)
#pragma unroll
    for (int q = 0; q < 4; ++q) {
      const int qq = kc * 4 + q;
      const int r2 = wv * 32 + 2 * qq;  // wave-uniform
      const float* g = mask + (size_t)(i0 + r2 + (lane >> 5)) * N + j0 + (lane & 31) * 4;
      load_lds16_nt((const void*)g, (void*)(smask + r2 * 128));
    }
#pragma unroll
    for (int fi = 0; fi < 4; ++fi)
#pragma unroll
      for (int fj = 0; fj < 4; ++fj) {
        acc[fi][fj] = __builtin_amdgcn_mfma_f32_16x16x32_bf16(ah[fi], bh[fj], acc[fi][fj], 0, 0, 0);
        acc[fi][fj] = __builtin_amdgcn_mfma_f32_16x16x32_bf16(ah[fi], bl[fj], acc[fi][fj], 0, 0, 0);
        acc[fi][fj] = __builtin_amdgcn_mfma_f32_16x16x32_bf16(al[fi], bh[fj], acc[fi][fj], 0, 0, 0);
      }
  }

  __syncthreads();  // drains global_load_lds; mask tile visible to all waves

  float sqj[4];
#pragma unroll
  for (int fj = 0; fj < 4; ++fj) sqj[fj] = sq[brow + fj * 16];

  float pp[4][4], cc[4][4];
#pragma unroll
  for (int a = 0; a < 4; ++a)
#pragma unroll
    for (int r = 0; r < 4; ++r) { pp[a][r] = 0.f; cc[a][r] = 0.f; }

#pragma unroll
  for (int fi = 0; fi < 4; ++fi) {
    float sqi[4];
#pragma unroll
    for (int r = 0; r < 4; ++r) sqi[r] = sq[i0 + wi * 64 + fi * 16 + lk * 4 + r];
#pragma unroll
    for (int fj = 0; fj < 4; ++fj) {
#pragma unroll
      for (int r = 0; r < 4; ++r) {
        float g = acc[fi][fj][r];
        float d2 = sqi[r] + sqj[fj] - 2.0f * g;
        float dist = d2 > 0.0f ? sqrtf(d2) : 0.0f;
        float m = smask[(wi * 64 + fi * 16 + lk * 4 + r) * 128 + wj * 64 + fj * 16 + lr];
        pp[fi][r] = fmaf(dist, m, pp[fi][r]);
        cc[fi][r] += m;
      }
    }
  }

  // reduce over the 16 lanes (= 16 cols x 4 fj already folded) sharing each row
#pragma unroll
  for (int fi = 0; fi < 4; ++fi)
#pragma unroll
    for (int r = 0; r < 4; ++r) {
#pragma unroll
      for (int off = 1; off < 16; off <<= 1) {
        pp[fi][r] += __shfl_xor(pp[fi][r], off);
        cc[fi][r] += __shfl_xor(cc[fi][r], off);
      }
    }

  __syncthreads();  // done reading smask; reuse it for the wj-combine
  float* cpos = smask;        // [128][2]
  float* ccnt = smask + 256;  // [128][2]
  if (lr == 0) {
#pragma unroll
    for (int fi = 0; fi < 4; ++fi)
#pragma unroll
      for (int r = 0; r < 4; ++r) {
        int r128 = wi * 64 + fi * 16 + lk * 4 + r;
        cpos[r128 * 2 + wj] = pp[fi][r];
        ccnt[r128 * 2 + wj] = cc[fi][r];
      }
  }
  __syncthreads();
  if (t < 128) {
    ppos[(size_t)jb * N + i0 + t] = cpos[t * 2] + cpos[t * 2 + 1];
    pcnt[(size_t)jb * N + i0 + t] = ccnt[t * 2] + ccnt[t * 2 + 1];
  }
}

// Kernel C1: per-row totals over the 64 column-block partials, then
// (pos_avg - nd) summed per block in double.
__global__ __launch_bounds__(256) void reduce1(
    const float* __restrict__ ppos, const float* __restrict__ pcnt,
    const float* __restrict__ nd, double* __restrict__ bsum) {
  const int b = blockIdx.x, t = threadIdx.x;
  const int row = b * 128 + (t >> 1);
  const int half = t & 1;
  float ps = 0.f, cs = 0.f;
  for (int jj = 0; jj < 32; ++jj) {
    int cb = half * 32 + jj;
    ps += ppos[(size_t)cb * N + row];
    cs += pcnt[(size_t)cb * N + row];
  }
  ps += __shfl_xor(ps, 1);
  cs += __shfl_xor(cs, 1);
  double v = 0.0;
  if (half == 0) v = (double)(ps / fmaxf(cs, 1.0f)) - (double)nd[row];
  __shared__ double sd[256];
  sd[t] = v;
  __syncthreads();
  for (int s = 128; s > 0; s >>= 1) {
    if (t < s) sd[t] += sd[t + s];
    __syncthreads();
  }
  if (t == 0) bsum[b] = sd[0];
}

// Kernel C2: sum 64 block partials, divide by N.
__global__ void reduce2(const double* __restrict__ bsum, float* __restrict__ out) {
  int lane = threadIdx.x;
  double v = bsum[lane];
#pragma unroll
  for (int off = 32; off; off >>= 1) v += __shfl_down(v, off);
  if (lane == 0) out[0] = (float)(v / (double)N);
}

extern "C" void kernel_launch(void* const* d_in, const int* in_sizes, int n_in,
                              void* d_out, int out_size, void* d_ws, size_t ws_size,
                              hipStream_t stream) {
  const float* pred = (const float*)d_in[0];
  const float* mask = (const float*)d_in[1];
  const float* neg  = (const float*)d_in[2];
  float* out = (float*)d_out;

  char* ws = (char*)d_ws;
  unsigned short* phi = (unsigned short*)ws;               ws += (size_t)N * D * 2;  // 2 MB
  unsigned short* plo = (unsigned short*)ws;               ws += (size_t)N * D * 2;  // 2 MB
  float* sq  = (float*)ws;                                 ws += (size_t)N * 4;
  float* nd  = (float*)ws;                                 ws += (size_t)N * 4;
  float* ppos = (float*)ws;                                ws += (size_t)64 * N * 4; // 2 MB
  float* pcnt = (float*)ws;                                ws += (size_t)64 * N * 4; // 2 MB
  double* bsum = (double*)ws;                              ws += 64 * 8;

  norm_kernel<<<N / 4, 256, 0, stream>>>(pred, neg, phi, plo, sq, nd);
  pair_kernel<<<(N / 128) * (N / 128), 256, 0, stream>>>(phi, plo, sq, mask, ppos, pcnt);
  reduce1<<<64, 256, 0, stream>>>(ppos, pcnt, nd, bsum);
  reduce2<<<1, 64, 0, stream>>>(bsum, out);
}